// Round 1
// baseline (190.646 us; speedup 1.0000x reference)
//
#include <hip/hip_runtime.h>
#include <hip/hip_bf16.h>

typedef __attribute__((ext_vector_type(8))) short bf16x8;
typedef __attribute__((ext_vector_type(4))) float f32x4;
typedef __attribute__((ext_vector_type(4))) short s16x4;

#define DEV static __device__ __forceinline__

DEV short f2bf(float f) {
    unsigned u = __builtin_bit_cast(unsigned, f);
    unsigned r = (u + 0x7fffu + ((u >> 16) & 1u)) >> 16;
    return (short)r;
}

DEV void gl_lds16(const void* g, void* l) {
    __builtin_amdgcn_global_load_lds(
        (const __attribute__((address_space(1))) unsigned*)g,
        (__attribute__((address_space(3))) unsigned*)l, 16, 0, 0);
}

DEV float wave_sum(float v) {
    #pragma unroll
    for (int off = 32; off; off >>= 1) v += __shfl_down(v, off, 64);
    return v;
}

DEV float block_sum(float v, float* sm, int t) {
    v = wave_sum(v);
    if ((t & 63) == 0) sm[t >> 6] = v;
    __syncthreads();
    float r = sm[0] + sm[1] + sm[2] + sm[3];
    __syncthreads();
    return r;
}

// ---------------- weight convert + transpose (fp32 [K][N] -> bf16 [N][K]) ----
__global__ __launch_bounds__(256) void transpose_w(const float* __restrict__ W,
                                                   short* __restrict__ out,
                                                   float scale) {
    __shared__ float tile[32][33];
    int t = threadIdx.x;
    int tx = t & 31, ty = t >> 5;  // 32 x 8
    int bx = blockIdx.x, by = blockIdx.y;
    #pragma unroll
    for (int i = 0; i < 4; i++) {
        int k = by * 32 + ty + i * 8;
        tile[ty + i * 8][tx] = W[(size_t)k * 1024 + bx * 32 + tx];
    }
    __syncthreads();
    #pragma unroll
    for (int i = 0; i < 4; i++) {
        int n = bx * 32 + ty + i * 8;
        int k = by * 32 + tx;
        out[(size_t)n * 1024 + k] = f2bf(tile[tx][ty + i * 8] * scale);
    }
}

// ---------------- LN(x) -> xln fp32 + bf16 --------------------------------
__global__ __launch_bounds__(256) void ln0_kernel(const float* __restrict__ x,
                                                  const float* __restrict__ g,
                                                  const float* __restrict__ b,
                                                  float* __restrict__ xln,
                                                  short* __restrict__ xbf) {
    __shared__ float sm[4];
    int row = blockIdx.x, t = threadIdx.x;
    const f32x4 v = *(const f32x4*)(x + (size_t)row * 1024 + t * 4);
    float mean = block_sum(v[0] + v[1] + v[2] + v[3], sm, t) * 0.0009765625f;
    f32x4 d;
    float sq = 0.f;
    #pragma unroll
    for (int j = 0; j < 4; j++) { d[j] = v[j] - mean; sq += d[j] * d[j]; }
    float var = block_sum(sq, sm, t) * 0.0009765625f;
    float inv = rsqrtf(var + 1e-5f);
    const f32x4 gv = *(const f32x4*)(g + t * 4);
    const f32x4 bv = *(const f32x4*)(b + t * 4);
    f32x4 o; s16x4 ob;
    #pragma unroll
    for (int j = 0; j < 4; j++) {
        float y = d[j] * inv * gv[j] + bv[j];
        o[j] = y; ob[j] = f2bf(y);
    }
    *(f32x4*)(xln + (size_t)row * 1024 + t * 4) = o;
    *(s16x4*)(xbf + (size_t)row * 1024 + t * 4) = ob;
}

// ---------------- dual LN: y = LN(xln+o)*gl+bl + LN(x+o)*gr+br -------------
__global__ __launch_bounds__(256) void ln_dual_kernel(
    const float* __restrict__ x, const float* __restrict__ xln,
    const float* __restrict__ o, const float* __restrict__ gl,
    const float* __restrict__ bl, const float* __restrict__ gr,
    const float* __restrict__ br, float* __restrict__ y,
    short* __restrict__ ybf) {
    __shared__ float sm[4];
    int row = blockIdx.x, t = threadIdx.x;
    size_t base = (size_t)row * 1024 + t * 4;
    const f32x4 xv = *(const f32x4*)(x + base);
    const f32x4 xl = *(const f32x4*)(xln + base);
    const f32x4 ov = *(const f32x4*)(o + base);
    f32x4 u, w;
    #pragma unroll
    for (int j = 0; j < 4; j++) { u[j] = xl[j] + ov[j]; w[j] = xv[j] + ov[j]; }
    float mu = block_sum(u[0] + u[1] + u[2] + u[3], sm, t) * 0.0009765625f;
    float mw = block_sum(w[0] + w[1] + w[2] + w[3], sm, t) * 0.0009765625f;
    float squ = 0.f, sqw = 0.f;
    #pragma unroll
    for (int j = 0; j < 4; j++) {
        u[j] -= mu; squ += u[j] * u[j];
        w[j] -= mw; sqw += w[j] * w[j];
    }
    float iu = rsqrtf(block_sum(squ, sm, t) * 0.0009765625f + 1e-5f);
    float iw = rsqrtf(block_sum(sqw, sm, t) * 0.0009765625f + 1e-5f);
    const f32x4 glv = *(const f32x4*)(gl + t * 4);
    const f32x4 blv = *(const f32x4*)(bl + t * 4);
    const f32x4 grv = *(const f32x4*)(gr + t * 4);
    const f32x4 brv = *(const f32x4*)(br + t * 4);
    f32x4 yo; s16x4 yb;
    #pragma unroll
    for (int j = 0; j < 4; j++) {
        float yy = u[j] * iu * glv[j] + blv[j] + w[j] * iw * grv[j] + brv[j];
        yo[j] = yy; yb[j] = f2bf(yy);
    }
    *(f32x4*)(y + base) = yo;
    *(s16x4*)(ybf + base) = yb;
}

// ---------------- final LN -> d_out ----------------------------------------
__global__ __launch_bounds__(256) void ln_final_kernel(const float* __restrict__ z,
                                                       const float* __restrict__ g,
                                                       const float* __restrict__ b,
                                                       float* __restrict__ out) {
    __shared__ float sm[4];
    int row = blockIdx.x, t = threadIdx.x;
    const f32x4 v = *(const f32x4*)(z + (size_t)row * 1024 + t * 4);
    float mean = block_sum(v[0] + v[1] + v[2] + v[3], sm, t) * 0.0009765625f;
    f32x4 d;
    float sq = 0.f;
    #pragma unroll
    for (int j = 0; j < 4; j++) { d[j] = v[j] - mean; sq += d[j] * d[j]; }
    float var = block_sum(sq, sm, t) * 0.0009765625f;
    float inv = rsqrtf(var + 1e-5f);
    const f32x4 gv = *(const f32x4*)(g + t * 4);
    const f32x4 bv = *(const f32x4*)(b + t * 4);
    f32x4 o;
    #pragma unroll
    for (int j = 0; j < 4; j++) o[j] = d[j] * inv * gv[j] + bv[j];
    *(f32x4*)(out + (size_t)row * 1024 + t * 4) = o;
}

// ---------------- GEMM: C[M][N] = A[M][K=1024] * Bt[N][K]^T ----------------
// MODE 0: QKV scatter.  MODE 1: bias+GELU -> bf16.  MODE 2: bias+resid -> f32.
template <int MODE>
__global__ __launch_bounds__(256, 2) void gemm_bt(
    const short* __restrict__ A, const short* __restrict__ Bt,
    short* __restrict__ outq, short* __restrict__ outk, short* __restrict__ outvt,
    const float* __restrict__ bias, short* __restrict__ outbf,
    const float* __restrict__ yresid, float* __restrict__ outz) {
    __shared__ short As[128 * 64];
    __shared__ short Bs[128 * 64];
    const int t = threadIdx.x;
    const int lane = t & 63;
    const int w = t >> 6;
    const int wr = w >> 1, wc = w & 1;
    const int l16 = lane & 15, lhi = lane >> 4;
    const int m0 = blockIdx.x * 128;
    const int n0 = blockIdx.y * 128;

    f32x4 acc[4][4] = {};

    for (int kt = 0; kt < 1024; kt += 64) {
        __syncthreads();
        #pragma unroll
        for (int i = 0; i < 4; i++) {
            int tt = i * 256 + t;
            int row = tt >> 3, c = tt & 7;
            int sw = ((c ^ (row & 7)) << 4);
            gl_lds16((const char*)A + ((size_t)(m0 + row) * 1024 + kt) * 2 + sw,
                     (char*)As + i * 4096 + w * 1024);
            gl_lds16((const char*)Bt + ((size_t)(n0 + row) * 1024 + kt) * 2 + sw,
                     (char*)Bs + i * 4096 + w * 1024);
        }
        __syncthreads();
        #pragma unroll
        for (int ks = 0; ks < 2; ks++) {
            bf16x8 af[4], bfr[4];
            #pragma unroll
            for (int mi = 0; mi < 4; mi++) {
                int row = wr * 64 + mi * 16 + l16;
                int c = (ks * 4 + lhi) ^ (row & 7);
                af[mi] = *(const bf16x8*)((const char*)As + row * 128 + c * 16);
            }
            #pragma unroll
            for (int ni = 0; ni < 4; ni++) {
                int row = wc * 64 + ni * 16 + l16;
                int c = (ks * 4 + lhi) ^ (row & 7);
                bfr[ni] = *(const bf16x8*)((const char*)Bs + row * 128 + c * 16);
            }
            #pragma unroll
            for (int mi = 0; mi < 4; mi++)
                #pragma unroll
                for (int ni = 0; ni < 4; ni++)
                    acc[mi][ni] = __builtin_amdgcn_mfma_f32_16x16x32_bf16(
                        af[mi], bfr[ni], acc[mi][ni], 0, 0, 0);
        }
    }

    #pragma unroll
    for (int mi = 0; mi < 4; mi++) {
        #pragma unroll
        for (int ni = 0; ni < 4; ni++) {
            #pragma unroll
            for (int r = 0; r < 4; r++) {
                int m = m0 + wr * 64 + mi * 16 + lhi * 4 + r;
                int n = n0 + wc * 64 + ni * 16 + l16;
                float vacc = acc[mi][ni][r];
                if (MODE == 0) {
                    int which = n >> 10, nn = n & 1023;
                    int h = nn >> 6, dh = nn & 63;
                    int b = m >> 10, s = m & 1023;
                    int bh = b * 16 + h;
                    if (which == 0)
                        outq[((size_t)bh * 1024 + s) * 64 + dh] = f2bf(vacc);
                    else if (which == 1)
                        outk[((size_t)bh * 1024 + s) * 64 + dh] = f2bf(vacc);
                    else
                        outvt[((size_t)bh * 64 + dh) * 1024 + s] = f2bf(vacc);
                } else if (MODE == 1) {
                    float hv = vacc + bias[n];
                    float ge = hv * 0.5f * (1.f + erff(hv * 0.70710678118654752f));
                    outbf[(size_t)m * 1024 + n] = f2bf(ge);
                } else {
                    outz[(size_t)m * 1024 + n] =
                        vacc + bias[n] + yresid[(size_t)m * 1024 + n];
                }
            }
        }
    }
}

// ---------------- flash attention ------------------------------------------
// block = (b,h, 64 q rows); 4 waves x 16 q rows; KV tiles of 64.
__global__ __launch_bounds__(256, 2) void attn_kernel(
    const short* __restrict__ qb, const short* __restrict__ kb,
    const short* __restrict__ vtb, float* __restrict__ obuf) {
    __shared__ short Qs[64 * 64];
    __shared__ short Ks[64 * 64];
    __shared__ short Vs[64 * 64];
    __shared__ short Ps[4 * 16 * 80];

    const int t = threadIdx.x, lane = t & 63, w = t >> 6;
    const int l16 = lane & 15, lhi = lane >> 4;
    const int blk = blockIdx.x;
    const int qt = blk & 15;
    const int bh = blk >> 4;
    const short* qp = qb + (size_t)bh * 1024 * 64 + (size_t)qt * 64 * 64;
    const short* kp = kb + (size_t)bh * 1024 * 64;
    const short* vp = vtb + (size_t)bh * 64 * 1024;

    #pragma unroll
    for (int i = 0; i < 2; i++) {
        int tt = i * 256 + t;
        int row = tt >> 3, c = tt & 7;
        gl_lds16((const char*)qp + row * 128 + ((c ^ (row & 7)) << 4),
                 (char*)Qs + i * 4096 + w * 1024);
    }
    __syncthreads();
    bf16x8 qa[2];
    #pragma unroll
    for (int d = 0; d < 2; d++) {
        int row = w * 16 + l16;
        int c = (d * 4 + lhi) ^ (row & 7);
        qa[d] = *(const bf16x8*)((const char*)Qs + row * 128 + c * 16);
    }

    f32x4 o[4] = {};
    float mrun[4], lrun[4];
    #pragma unroll
    for (int r = 0; r < 4; r++) { mrun[r] = -1e30f; lrun[r] = 0.f; }

    short* pw = Ps + w * 16 * 80;

    for (int kv = 0; kv < 16; kv++) {
        __syncthreads();
        #pragma unroll
        for (int i = 0; i < 2; i++) {
            int tt = i * 256 + t;
            int row = tt >> 3, c = tt & 7;
            int sw = ((c ^ (row & 7)) << 4);
            gl_lds16((const char*)kp + (size_t)(kv * 64 + row) * 128 + sw,
                     (char*)Ks + i * 4096 + w * 1024);
            gl_lds16((const char*)vp + (size_t)row * 2048 + kv * 128 + sw,
                     (char*)Vs + i * 4096 + w * 1024);
        }
        __syncthreads();

        f32x4 sc[4];
        #pragma unroll
        for (int kvb = 0; kvb < 4; kvb++) {
            f32x4 s4 = {};
            #pragma unroll
            for (int d = 0; d < 2; d++) {
                int row = kvb * 16 + l16;
                int c = (d * 4 + lhi) ^ (row & 7);
                bf16x8 kf = *(const bf16x8*)((const char*)Ks + row * 128 + c * 16);
                s4 = __builtin_amdgcn_mfma_f32_16x16x32_bf16(qa[d], kf, s4, 0, 0, 0);
            }
            sc[kvb] = s4;
        }

        #pragma unroll
        for (int r = 0; r < 4; r++) {
            float mx = fmaxf(fmaxf(sc[0][r], sc[1][r]), fmaxf(sc[2][r], sc[3][r]));
            #pragma unroll
            for (int off = 8; off; off >>= 1) mx = fmaxf(mx, __shfl_xor(mx, off, 64));
            float nm = fmaxf(mrun[r], mx);
            float corr = __expf(mrun[r] - nm);
            float rs = 0.f;
            #pragma unroll
            for (int kvb = 0; kvb < 4; kvb++) {
                float p = __expf(sc[kvb][r] - nm);
                sc[kvb][r] = p;
                rs += p;
            }
            #pragma unroll
            for (int off = 8; off; off >>= 1) rs += __shfl_xor(rs, off, 64);
            lrun[r] = lrun[r] * corr + rs;
            mrun[r] = nm;
            #pragma unroll
            for (int d = 0; d < 4; d++) o[d][r] *= corr;
            #pragma unroll
            for (int kvb = 0; kvb < 4; kvb++)
                pw[(lhi * 4 + r) * 80 + kvb * 16 + l16] = f2bf(sc[kvb][r]);
        }

        bf16x8 pa[2];
        #pragma unroll
        for (int kk = 0; kk < 2; kk++)
            pa[kk] = *(const bf16x8*)((const char*)pw + l16 * 160 + kk * 64 + lhi * 16);
        #pragma unroll
        for (int d = 0; d < 4; d++) {
            #pragma unroll
            for (int kk = 0; kk < 2; kk++) {
                int vrow = d * 16 + l16;
                int c = (kk * 4 + lhi) ^ (vrow & 7);
                bf16x8 vf = *(const bf16x8*)((const char*)Vs + vrow * 128 + c * 16);
                o[d] = __builtin_amdgcn_mfma_f32_16x16x32_bf16(pa[kk], vf, o[d], 0, 0, 0);
            }
        }
    }

    const int b = bh >> 4, h = bh & 15;
    #pragma unroll
    for (int d = 0; d < 4; d++) {
        #pragma unroll
        for (int r = 0; r < 4; r++) {
            int s = qt * 64 + w * 16 + lhi * 4 + r;
            int dh = d * 16 + l16;
            obuf[((size_t)(b * 1024 + s)) * 1024 + h * 64 + dh] = o[d][r] / lrun[r];
        }
    }
}

// ---------------------------------------------------------------------------
extern "C" void kernel_launch(void* const* d_in, const int* in_sizes, int n_in,
                              void* d_out, int out_size, void* d_ws, size_t ws_size,
                              hipStream_t stream) {
    const float* x  = (const float*)d_in[0];
    const float* Wq = (const float*)d_in[1];
    const float* Wk = (const float*)d_in[2];
    const float* Wv = (const float*)d_in[3];
    const float* g0 = (const float*)d_in[4];
    const float* b0 = (const float*)d_in[5];
    const float* gl = (const float*)d_in[6];
    const float* bl = (const float*)d_in[7];
    const float* gr = (const float*)d_in[8];
    const float* br = (const float*)d_in[9];
    const float* gf = (const float*)d_in[10];
    const float* bfp = (const float*)d_in[11];
    const float* W1 = (const float*)d_in[12];
    const float* b1 = (const float*)d_in[13];
    const float* W2 = (const float*)d_in[14];
    const float* b2 = (const float*)d_in[15];

    char* ws = (char*)d_ws;
    float* xln   = (float*)(ws);                          // 16 MB
    short* xlnbf = (short*)(ws + ((size_t)16 << 20));     //  8 MB
    short* wqkvT = (short*)(ws + ((size_t)24 << 20));     //  6 MB
    short* w1T   = (short*)(ws + ((size_t)30 << 20));     //  2 MB
    short* w2T   = (short*)(ws + ((size_t)32 << 20));     //  2 MB
    short* qb    = (short*)(ws + ((size_t)34 << 20));     //  8 MB
    short* kb    = (short*)(ws + ((size_t)42 << 20));     //  8 MB
    short* vtb   = (short*)(ws + ((size_t)50 << 20));     //  8 MB
    float* obuf  = (float*)(ws + ((size_t)58 << 20));     // 16 MB
    float* ybuf  = (float*)(ws + ((size_t)74 << 20));     // 16 MB
    short* ybf   = (short*)(ws + ((size_t)90 << 20));     //  8 MB
    short* hbf   = (short*)(ws + ((size_t)98 << 20));     //  8 MB
    float* zbuf  = (float*)(ws + ((size_t)106 << 20));    // 16 MB

    dim3 b256(256);
    transpose_w<<<dim3(32, 32), b256, 0, stream>>>(Wq, wqkvT, 0.125f);
    transpose_w<<<dim3(32, 32), b256, 0, stream>>>(Wk, wqkvT + (size_t)1024 * 1024, 1.f);
    transpose_w<<<dim3(32, 32), b256, 0, stream>>>(Wv, wqkvT + (size_t)2 * 1024 * 1024, 1.f);
    transpose_w<<<dim3(32, 32), b256, 0, stream>>>(W1, w1T, 1.f);
    transpose_w<<<dim3(32, 32), b256, 0, stream>>>(W2, w2T, 1.f);

    ln0_kernel<<<4096, b256, 0, stream>>>(x, g0, b0, xln, xlnbf);

    gemm_bt<0><<<dim3(32, 24), b256, 0, stream>>>(xlnbf, wqkvT, qb, kb, vtb,
                                                  nullptr, nullptr, nullptr, nullptr);

    attn_kernel<<<1024, b256, 0, stream>>>(qb, kb, vtb, obuf);

    ln_dual_kernel<<<4096, b256, 0, stream>>>(x, xln, obuf, gl, bl, gr, br, ybuf, ybf);

    gemm_bt<1><<<dim3(32, 8), b256, 0, stream>>>(ybf, w1T, nullptr, nullptr, nullptr,
                                                 b1, hbf, nullptr, nullptr);

    gemm_bt<2><<<dim3(32, 8), b256, 0, stream>>>(hbf, w2T, nullptr, nullptr, nullptr,
                                                 b2, nullptr, ybuf, zbuf);

    ln_final_kernel<<<4096, b256, 0, stream>>>(zbuf, gf, bfp, (float*)d_out);
}